// Round 9
// baseline (619.424 us; speedup 1.0000x reference)
//
#include <hip/hip_runtime.h>

#define N_NODES  100000
#define N_EDGES  1600000
#define HIDDEN   128
#define STEPS    4
#define N_GRAPHS 64
#define NBUCK    256
#define BWID     391   // nodes per bucket: 256*391 = 100096 >= 100000 (<512 -> 9 bits)
#define BCAP     7168  // fixed ebuf slots per bucket (mean 6250, +11 sigma)
#define SLABU    1600016   // u16 per column-slab: (N_NODES+1) * 16
#define SLABB    3200032   // bytes per slab

typedef unsigned short u16;
typedef unsigned int   u32;
typedef unsigned long long u64;
typedef __attribute__((ext_vector_type(8))) short bf16x8;
typedef __attribute__((ext_vector_type(4))) float f32x4;
typedef __attribute__((ext_vector_type(2))) float f32x2;

__device__ inline u16 f2bf(float f) {
  u32 u = __float_as_uint(f);
  u = (u + 0x7FFFu + ((u >> 16) & 1u)) >> 16;  // RTNE
  return (u16)u;
}
__device__ inline float bf2f(u16 b) { return __uint_as_float(((u32)b) << 16); }

// rcp-based activations: no IEEE division sequence, no clamps.
__device__ inline float rcp_f(float x) { return __builtin_amdgcn_rcpf(x); }
__device__ inline float sig_f(float x) { return rcp_f(1.f + __expf(-x)); }
__device__ inline float tanh_f(float x) { return 1.f - 2.f * rcp_f(1.f + __expf(2.f * x)); }

// ---------------- CSR build (bucketed multisplit, fixed-capacity buckets) ----------------
__global__ __launch_bounds__(1024) void k_part(const int* __restrict__ esrc,
                                               const int* __restrict__ edst,
                                               int* __restrict__ gcursor,
                                               u32* __restrict__ ebuf) {
  __shared__ int hist[16][NBUCK];   // 16 KB
  __shared__ int base[16][NBUCK];   // 16 KB
  int tid = threadIdx.x;
  int wv  = tid >> 6;
  #pragma unroll
  for (int i = 0; i < 4; ++i) ((int*)hist)[tid + i * 1024] = 0;
  __syncthreads();
  int e0 = blockIdx.x * 4096;
  int sv[4], dv[4], bk[4], rk[4];
  #pragma unroll
  for (int i = 0; i < 4; ++i) {
    int e = e0 + i * 1024 + tid;
    if (e < N_EDGES) {
      sv[i] = esrc[e];
      dv[i] = edst[e];
      bk[i] = (int)((u32)dv[i] / (u32)BWID);
      rk[i] = atomicAdd(&hist[wv][bk[i]], 1);
    } else bk[i] = -1;
  }
  __syncthreads();
  if (tid < NBUCK) {
    int c[16];
    int sum = 0;
    #pragma unroll
    for (int w = 0; w < 16; ++w) { c[w] = hist[w][tid]; sum += c[w]; }
    int g = atomicAdd(&gcursor[tid], sum);
    #pragma unroll
    for (int w = 0; w < 16; ++w) { base[w][tid] = g; g += c[w]; }
  }
  __syncthreads();
  #pragma unroll
  for (int i = 0; i < 4; ++i) {
    if (bk[i] >= 0) {
      int pos = bk[i] * BCAP + base[wv][bk[i]] + rk[i];
      ebuf[pos] = ((u32)(dv[i] - bk[i] * BWID) << 17) | (u32)sv[i];
    }
  }
}

// Scan bucket counts -> ebase; also zero the pool accumulator (saves a dispatch).
__global__ void k_bscan(const int* __restrict__ gcursor, int* __restrict__ ebase,
                        float* __restrict__ acc) {
  __shared__ int buf[NBUCK];
  int t = threadIdx.x;
  int v = gcursor[t];
  buf[t] = v;
  __syncthreads();
  for (int off = 1; off < NBUCK; off <<= 1) {
    int u = 0;
    if (t >= off) u = buf[t - off];
    __syncthreads();
    buf[t] += u;
    __syncthreads();
  }
  ebase[t] = buf[t] - v;
  if (t == NBUCK - 1) ebase[NBUCK] = buf[t];
  for (int i = t; i < N_GRAPHS * HIDDEN; i += NBUCK) acc[i] = 0.f;
}

__global__ __launch_bounds__(1024) void k_csr(const u32* __restrict__ ebuf,
                                              const int* __restrict__ ebase,
                                              int* __restrict__ offs,
                                              int* __restrict__ csr) {
  __shared__ int lcnt[512];
  __shared__ int lofs[512];
  int b = blockIdx.x, tid = threadIdx.x;
  int n0 = b * BWID;
  int n1 = min(n0 + BWID, N_NODES);
  int nn = n1 - n0;
  int e0 = ebase[b];
  int cnt = ebase[b + 1] - e0;
  const u32* ebase_p = ebuf + (size_t)b * BCAP;
  if (tid < 512) lcnt[tid] = 0;
  __syncthreads();
  for (int e = tid; e < cnt; e += 1024) {
    int dst = (int)(ebase_p[e] >> 17);   // bucket-local
    atomicAdd(&lcnt[dst], 1);
  }
  __syncthreads();
  if (tid < 512) lofs[tid] = lcnt[tid];
  __syncthreads();
  for (int off = 1; off < 512; off <<= 1) {
    int v = 0;
    if (tid < 512 && tid >= off) v = lofs[tid - off];
    __syncthreads();
    if (tid < 512 && tid >= off) lofs[tid] += v;
    __syncthreads();
  }
  int nodeoff = 0;
  if (tid < 512) nodeoff = e0 + lofs[tid] - lcnt[tid];  // exclusive
  if (tid < 512) lofs[tid] = nodeoff;                   // reuse as cursor
  if (tid < nn) offs[n0 + tid] = nodeoff;
  if (b == 0 && tid == 0) offs[N_NODES] = N_EDGES;
  __syncthreads();
  for (int e = tid; e < cnt; e += 1024) {
    u32 p = ebase_p[e];
    int src = (int)(p & 0x1FFFFu);
    int dst = (int)(p >> 17);
    int pos = atomicAdd(&lofs[dst], 1);
    csr[pos] = src;
  }
}

// ---------------- combined weight build + x->bf16 convert (merged dispatch) ----------------
// Blocks [0,1024): weight build (128 active threads). Blocks [1024, 1024+12500):
// convert x into SLAB layout (8 slabs of (N_NODES+1) x 16 cols) + zero dummy rows.
__global__ void k_wbc(const float* __restrict__ W, const float* __restrict__ w_ih,
                      const float* __restrict__ w_hh, u16* __restrict__ bsw,
                      const float* __restrict__ x, u16* __restrict__ h0,
                      u16* __restrict__ h1) {
  __shared__ float wrow[128];
  if (blockIdx.x >= 1024) {
    int bb = blockIdx.x - 1024;
    int i = (bb * 256 + threadIdx.x) * 4;
    float4 v = *(const float4*)(x + i);
    u16 o[4] = {f2bf(v.x), f2bf(v.y), f2bf(v.z), f2bf(v.w)};
    int row = i >> 7, col = i & 127;
    *(uint2*)(h0 + (size_t)(col >> 4) * SLABU + (size_t)row * 16 + (col & 15)) = *(uint2*)o;
    if (bb == 0) {
      int t = threadIdx.x;
      if (t < 64) {
        ((u32*)h0)[(size_t)(t >> 3) * (SLABU / 2) + (N_NODES * 8) + (t & 7)] = 0;
      } else if (t < 128) {
        int tt = t - 64;
        ((u32*)h1)[(size_t)(tt >> 3) * (SLABU / 2) + (N_NODES * 8) + (tt & 7)] = 0;
      }
    }
    return;
  }
  int b = blockIdx.x, st = b >> 8, k = b & 255, t = threadIdx.x;
  if (t >= 128) return;
  if (k < 128) wrow[t] = W[(st * 128 + k) * 128 + t];
  __syncthreads();
  int kc = k >> 5, quad = (k >> 3) & 3, kl = k & 7;
  u16* base = bsw + (size_t)st * 131072 + kc * 16384;
  #pragma unroll
  for (int gq = 0; gq < 4; ++gq) {
    int c = gq * 128 + t;
    float v;
    if (k < 128) {
      if (c < 384) {
        const float* wr = w_ih + c * 128;
        float sacc = 0.f;
        for (int j = 0; j < 128; ++j) sacc += wrow[j] * wr[j];
        v = sacc;
      } else v = 0.f;
    } else {
      int kk = k - 128;
      if (c < 256)      v = w_hh[c * 128 + kk];
      else if (c < 384) v = 0.f;
      else              v = w_hh[(c - 128) * 128 + kk];
    }
    int gi = c >> 7, cw = c & 127;
    int wv = cw >> 5, hu = (cw >> 4) & 1, nl = c & 15;
    int slot = wv * 8 + gi * 2 + hu;
    base[(slot * 4 + quad) * 128 + nl * 8 + kl] = f2bf(v);
  }
}

// ---------------- gather helpers ----------------
__device__ inline void acc8(f32x2* a, uint4 p) {
  f32x2 v;
  v.x = __uint_as_float(p.x << 16); v.y = __uint_as_float(p.x & 0xffff0000u);
  a[0] += v;
  v.x = __uint_as_float(p.y << 16); v.y = __uint_as_float(p.y & 0xffff0000u);
  a[1] += v;
  v.x = __uint_as_float(p.z << 16); v.y = __uint_as_float(p.z & 0xffff0000u);
  a[2] += v;
  v.x = __uint_as_float(p.w << 16); v.y = __uint_as_float(p.w & 0xffff0000u);
  a[3] += v;
}
__device__ inline uint4 ldrow(const char* hb, u32 off) {
  return *(const uint4*)(hb + off);
}

// ---------------- XCD-sliced gather: s[dst][slice] = sum h[src][slice] ----------------
// Grid = 3125 node-tiles x 8 column-slices, slice = blockIdx & 7 so the 8 XCDs'
// round-robin workgroup dispatch pins each 3.2 MB column slab to one XCD's 4 MB L2:
// h cold-fetches once (dense slab lines), all edge re-reads are L2 hits — breaking
// the 3.5 TB/s random-row HBM wall measured in R0/R7.
// Per wave: 8 nodes; per node: 4 edge-slots x 2 half-lanes (16 B each).
__global__ void k_gather_sliced(const u16* __restrict__ h, const int* __restrict__ csr,
                                const int* __restrict__ offs, u16* __restrict__ s) {
  __shared__ int soffs[33];
  const int tid   = threadIdx.x;
  const int slice = blockIdx.x & 7;
  const int tile  = blockIdx.x >> 3;
  const int row0  = tile * 32;
  if (tid < 33) soffs[tid] = offs[row0 + tid];
  __syncthreads();
  const int wave = tid >> 6;
  const int lane = tid & 63;
  const int no   = lane >> 3;        // node within wave (0..7)
  const int slot = (lane >> 1) & 3;  // edge slot (0..3)
  const int hf   = lane & 1;         // half of the 32B slice
  const int n    = wave * 8 + no;    // local node (0..31)
  const char* hb = (const char*)h + (size_t)slice * SLABB;
  const u32 co   = (u32)(hf << 4);
  int beg = soffs[n], end = soffs[n + 1];
  int dm = end - beg;
  dm = max(dm, __shfl_xor(dm, 8));
  dm = max(dm, __shfl_xor(dm, 16));
  dm = max(dm, __shfl_xor(dm, 32));   // wave-max degree -> uniform trip count
  int iters = (dm + 7) >> 3;
  f32x2 a[4];
  a[0] = a[1] = a[2] = a[3] = (f32x2){0.f, 0.f};
  int j0 = beg + slot;
  #pragma unroll 1
  for (int t = 0; t < iters; ++t) {
    int ja = j0 + t * 8;
    int jb = ja + 4;
    u32 sa = (u32)csr[ja < end ? ja : 0];
    u32 sb = (u32)csr[jb < end ? jb : 0];
    sa = (ja < end) ? sa : (u32)N_NODES;   // dummy zero row pads
    sb = (jb < end) ? sb : (u32)N_NODES;
    uint4 ra = ldrow(hb, (sa << 5) | co);
    uint4 rb = ldrow(hb, (sb << 5) | co);
    acc8(a, ra);
    acc8(a, rb);
  }
  #pragma unroll
  for (int r = 0; r < 4; ++r) {   // reduce over the 4 edge slots (lane bits 1,2)
    a[r].x += __shfl_xor(a[r].x, 2); a[r].y += __shfl_xor(a[r].y, 2);
    a[r].x += __shfl_xor(a[r].x, 4); a[r].y += __shfl_xor(a[r].y, 4);
  }
  if ((lane & 6) == 0) {   // slot==0 lanes: one 16B store per (node, half)
    uint4 o;
    o.x = (u32)f2bf(a[0].x) | ((u32)f2bf(a[0].y) << 16);
    o.y = (u32)f2bf(a[1].x) | ((u32)f2bf(a[1].y) << 16);
    o.z = (u32)f2bf(a[2].x) | ((u32)f2bf(a[2].y) << 16);
    o.w = (u32)f2bf(a[3].x) | ((u32)f2bf(a[3].y) << 16);
    *(uint4*)(s + (size_t)slice * SLABU + (size_t)(row0 + n) * 16 + hf * 8) = o;
  }
}

// ---------------- fused dual-GEMM + GRU cell (R15-frozen core, slab I/O) ----------------
__global__ __launch_bounds__(256, 2) void k_gemm_gru(
    const u16* __restrict__ s_mat, const u16* __restrict__ h_mat,
    const u16* __restrict__ bsw, const float* __restrict__ b_ih,
    const float* __restrict__ b_hh, u16* __restrict__ h_out) {
  __shared__ u16 Asw[8192];       // 16 KB: A=[s|h], 32 rows x 256 k, frag-ordered

  const int tid  = threadIdx.x;
  const int wave = tid >> 6;
  const int lane = tid & 63;
  const int nl   = lane & 15;
  const int quad = lane >> 4;
  const int row0 = blockIdx.x * 32;   // 3125 * 32 == 100000 exactly

  {  // stage A from slab layout (same elements -> same Asw slots as R15)
    int snl = tid & 15, squad = (tid >> 4) & 3, sel = tid >> 6;
    int g = sel & 1, half = sel >> 1;
    const u16* mat = half ? h_mat : s_mat;
    size_t r = (size_t)(row0 + g * 16 + snl);
    #pragma unroll
    for (int kc2 = 0; kc2 < 4; ++kc2) {
      int slab = kc2 * 2 + (squad >> 1);
      uint4 v = *(const uint4*)(mat + (size_t)slab * SLABU + r * 16 + (squad & 1) * 8);
      *(uint4*)&Asw[(((g * 8 + half * 4 + kc2) * 4 + squad) * 16 + snl) * 8] = v;
    }
  }
  __syncthreads();

  const u16* bp = bsw + wave * 8 * 512 + lane * 8;

  f32x4 acc[2][8];
  #pragma unroll
  for (int g = 0; g < 2; ++g)
    #pragma unroll
    for (int u = 0; u < 8; ++u) acc[g][u] = (f32x4){0.f, 0.f, 0.f, 0.f};

  bf16x8 b0[6], b1[6], b2[6];
  #pragma unroll
  for (int i = 0; i < 6; ++i) b0[i] = *(const bf16x8*)(bp + i * 512);
  #pragma unroll
  for (int i = 0; i < 6; ++i) b1[i] = *(const bf16x8*)(bp + 16384 + i * 512);

  #pragma unroll
  for (int kc = 0; kc < 8; ++kc) {
    if (kc < 6) {
      #pragma unroll
      for (int i = 0; i < 6; ++i) {
        int us = (kc + 2 < 4) ? i : (i < 4 ? i : i + 2);
        b2[i] = *(const bf16x8*)(bp + (kc + 2) * 16384 + us * 512);
      }
    }
    bf16x8 a0 = *(const bf16x8*)&Asw[kc * 512 + lane * 8];
    bf16x8 a1 = *(const bf16x8*)&Asw[(8 + kc) * 512 + lane * 8];
    #pragma unroll
    for (int i = 0; i < 6; ++i) {
      int u = (kc < 4) ? i : (i < 4 ? i : i + 2);
      acc[0][u] = __builtin_amdgcn_mfma_f32_16x16x32_bf16(a0, b0[i], acc[0][u], 0, 0, 0);
      acc[1][u] = __builtin_amdgcn_mfma_f32_16x16x32_bf16(a1, b0[i], acc[1][u], 0, 0, 0);
    }
    #pragma unroll
    for (int i = 0; i < 6; ++i) { b0[i] = b1[i]; b1[i] = b2[i]; }
  }

  float bias[8];
  #pragma unroll
  for (int u = 0; u < 8; ++u) {
    int gi = u >> 1, hu = u & 1;
    int cw = wave * 32 + hu * 16 + nl;
    bias[u] = (gi == 0) ? b_ih[cw] + b_hh[cw]
            : (gi == 1) ? b_ih[128 + cw] + b_hh[128 + cw]
            : (gi == 2) ? b_ih[256 + cw]
                        : b_hh[256 + cw];
  }

  #pragma unroll
  for (int g = 0; g < 2; ++g) {
    #pragma unroll
    for (int hu = 0; hu < 2; ++hu) {
      int cw = wave * 32 + hu * 16 + nl;
      int slab = wave * 2 + hu;            // cw >> 4
      int hbase = ((g * 8 + 4 + wave) * 4 + ((hu * 2 + (nl >> 3)) & 3)) * 128 + (nl & 7);
      #pragma unroll
      for (int i = 0; i < 4; ++i) {
        int m = quad * 4 + i;
        float rv = sig_f(acc[g][0 + hu][i] + bias[0 + hu]);
        float zv = sig_f(acc[g][2 + hu][i] + bias[2 + hu]);
        float iv = acc[g][4 + hu][i] + bias[4 + hu];
        float hn = acc[g][6 + hu][i] + bias[6 + hu];
        float hv = bf2f(Asw[hbase + m * 8]);
        float n  = tanh_f(iv + rv * hn);
        float o  = n + zv * (hv - n);
        h_out[(size_t)slab * SLABU + (size_t)(row0 + g * 16 + m) * 16 + nl] = f2bf(o);
      }
    }
  }
}

// ---------------- relu + segment mean pool (two-phase, parallel; slab reads) ----------------
__global__ void k_pool_partial(const u16* __restrict__ h, const int* __restrict__ batch,
                               float* __restrict__ acc) {
  int t = threadIdx.x;  // column 0..127
  size_t cbase = (size_t)(t >> 4) * SLABU + (t & 15);
  int node0 = blockIdx.x * 80;
  int node1 = node0 + 80;
  int cur = batch[node0];
  float sum = 0.f;
  for (int r = node0; r < node1; ++r) {
    int g = batch[r];
    if (g != cur) {
      atomicAdd(&acc[cur * 128 + t], sum);
      sum = 0.f;
      cur = g;
    }
    sum += fmaxf(bf2f(h[cbase + (size_t)r * 16]), 0.f);
  }
  atomicAdd(&acc[cur * 128 + t], sum);
}

__global__ void k_pool_div(const float* __restrict__ acc, const int* __restrict__ batch,
                           float* __restrict__ out) {
  __shared__ int se[2];
  int g = blockIdx.x, t = threadIdx.x;
  if (t < 2) {
    int target = g + t;
    int lo = 0, hi = N_NODES;
    while (lo < hi) { int mid = (lo + hi) >> 1; if (batch[mid] < target) lo = mid + 1; else hi = mid; }
    se[t] = lo;
  }
  __syncthreads();
  int cnt = se[1] - se[0];
  out[g * 128 + t] = acc[g * 128 + t] / (float)(cnt > 0 ? cnt : 1);
}

extern "C" void kernel_launch(void* const* d_in, const int* in_sizes, int n_in,
                              void* d_out, int out_size, void* d_ws, size_t ws_size,
                              hipStream_t stream) {
  const float* x     = (const float*)d_in[0];
  const int*   edges = (const int*)d_in[1];
  const int*   batch = (const int*)d_in[2];
  const float* W     = (const float*)d_in[3];
  const float* w_ih  = (const float*)d_in[4];
  const float* w_hh  = (const float*)d_in[5];
  const float* b_ih  = (const float*)d_in[6];
  const float* b_hh  = (const float*)d_in[7];
  float* out = (float*)d_out;

  char* w = (char*)d_ws;
  u16* buf0    = (u16*)(w);                 // 25,600,256 B = 8 slabs (h/s ping)
  u16* buf1    = (u16*)(w + 25600256);      // 25,600,256 B = 8 slabs (h/s pong)
  u16* bsw     = (u16*)(w + 51200512);      // 1,048,576 B
  float* acc   = (float*)(w + 52249088);    // 32,768 B  (pool accumulator)
  int* offs    = (int*)(w + 52281856);      // 400,004 B
  int* gcursor = (int*)(w + 52682240);      // 1,024 B
  int* ebase   = (int*)(w + 52683264);      // 1,028 B
  int* csr     = (int*)(w + 52684800);      // 6,400,000 B -> total ~59.1 MB
  u32* ebuf    = (u32*)buf1;                // 7.3 MB; fully consumed before buf1 h-use

  const int* esrc = edges;
  const int* edst = edges + N_EDGES;

  hipMemsetAsync(gcursor, 0, NBUCK * sizeof(int), stream);
  k_part<<<391, 1024, 0, stream>>>(esrc, edst, gcursor, ebuf);
  k_bscan<<<1, NBUCK, 0, stream>>>(gcursor, ebase, acc);
  k_csr<<<NBUCK, 1024, 0, stream>>>(ebuf, ebase, offs, csr);
  k_wbc<<<1024 + (N_NODES * HIDDEN) / 1024, 256, 0, stream>>>(W, w_ih, w_hh, bsw,
                                                              x, buf0, buf1);

  u16* hcur = buf0;
  u16* hnxt = buf1;
  for (int st = 0; st < STEPS; ++st) {
    // sliced gather: reads hcur slabs (per-XCD L2-resident), writes s slabs to hnxt
    k_gather_sliced<<<(N_NODES / 32) * 8, 256, 0, stream>>>(hcur, csr, offs, hnxt);
    // in-place: each block stages its own 32 rows of s (hnxt) and h (hcur) to LDS,
    // then writes h_out over exactly those slab words of hnxt.
    k_gemm_gru<<<N_NODES / 32, 256, 0, stream>>>(hnxt, hcur, bsw + st * 131072,
                                                 b_ih, b_hh, hnxt);
    u16* tmp = hcur; hcur = hnxt; hnxt = tmp;
  }
  k_pool_partial<<<1250, 128, 0, stream>>>(hcur, batch, acc);
  k_pool_div<<<N_GRAPHS, 128, 0, stream>>>(acc, batch, out);
}